// Round 1
// baseline (979.253 us; speedup 1.0000x reference)
//
#include <hip/hip_runtime.h>
#include <stdint.h>

#define V_SZ 50000
#define H_DIM 1024
#define F_DIM 4096
#define E_NUM 8
#define S_LEN 128
#define N_TOK 4096
#define NPAD (N_TOK + E_NUM*128)

typedef unsigned short u16;
typedef unsigned int u32;
typedef short bf16x8 __attribute__((ext_vector_type(8)));
typedef float f32x4 __attribute__((ext_vector_type(4)));

__device__ __forceinline__ u16 f2bf(float f) {
  u32 u = __builtin_bit_cast(u32, f);
  u += 0x7fffu + ((u >> 16) & 1u);   // RNE; inputs finite
  return (u16)(u >> 16);
}
__device__ __forceinline__ u32 pack2(float a, float b) {
  return (u32)f2bf(a) | ((u32)f2bf(b) << 16);
}

// async global->LDS, 16B per lane; LDS dest must be wave-uniform base (HW adds lane*16)
__device__ __forceinline__ void gld_lds16(u16* lds, const u16* g) {
  __builtin_amdgcn_global_load_lds((const __attribute__((address_space(1))) void*)g,
                                   (__attribute__((address_space(3))) void*)lds,
                                   16, 0, 0);
}

// ---------------- pooling: h[n] = mean_s emb[x[n,s]] ----------------
__global__ void pool_kernel(const int* __restrict__ x, const float* __restrict__ emb,
                            float* __restrict__ h) {
  __shared__ int sidx[S_LEN];
  const int n = blockIdx.x, t = threadIdx.x;
  if (t < S_LEN) sidx[t] = x[n*S_LEN + t];
  __syncthreads();
  float4 acc = make_float4(0.f, 0.f, 0.f, 0.f);
  #pragma unroll 4
  for (int s = 0; s < S_LEN; ++s) {
    const float4* e4 = (const float4*)(emb + (size_t)sidx[s]*H_DIM);
    float4 v = e4[t];
    acc.x += v.x; acc.y += v.y; acc.z += v.z; acc.w += v.w;
  }
  const float sc = 1.0f/(float)S_LEN;
  float4 o = make_float4(acc.x*sc, acc.y*sc, acc.z*sc, acc.w*sc);
  ((float4*)h)[(size_t)n*(H_DIM/4) + t] = o;
}

// ---------------- gating: softmax(h@Wg) top-1 ----------------
__global__ void gate_kernel(const float* __restrict__ h, const float* __restrict__ Wg,
                            float* __restrict__ gate_val, int* __restrict__ gate_idx,
                            int* __restrict__ cnt) {
  const int n = blockIdx.x, l = threadIdx.x;   // 64 threads
  const float* hn = h + (size_t)n*H_DIM;
  float acc[E_NUM];
  #pragma unroll
  for (int e = 0; e < E_NUM; ++e) acc[e] = 0.f;
  for (int j = 0; j < H_DIM/64; ++j) {
    const int hh = j*64 + l;
    const float v = hn[hh];
    const float4* w4 = (const float4*)(Wg + (size_t)hh*E_NUM);
    const float4 wa = w4[0], wb = w4[1];
    acc[0] += v*wa.x; acc[1] += v*wa.y; acc[2] += v*wa.z; acc[3] += v*wa.w;
    acc[4] += v*wb.x; acc[5] += v*wb.y; acc[6] += v*wb.z; acc[7] += v*wb.w;
  }
  #pragma unroll
  for (int m = 32; m >= 1; m >>= 1) {
    #pragma unroll
    for (int e = 0; e < E_NUM; ++e) acc[e] += __shfl_xor(acc[e], m);
  }
  if (l == 0) {
    float mx = acc[0]; int im = 0;
    #pragma unroll
    for (int e = 1; e < E_NUM; ++e) if (acc[e] > mx) { mx = acc[e]; im = e; }
    float s = 0.f;
    #pragma unroll
    for (int e = 0; e < E_NUM; ++e) s += expf(acc[e] - mx);
    gate_val[n] = 1.0f / s;       // softmax prob of argmax
    gate_idx[n] = im;
    atomicAdd(&cnt[im], 1);
  }
}

// ---------------- expert segment offsets (padded to 128) ----------------
__global__ void offsets_kernel(const int* __restrict__ cnt, int* __restrict__ pad_off) {
  int o = 0;
  for (int e = 0; e < E_NUM; ++e) {
    pad_off[e] = o;
    o += ((cnt[e] + 127) >> 7) << 7;
  }
  pad_off[E_NUM] = o;
}

__global__ void scatter_kernel(const int* __restrict__ gate_idx, const int* __restrict__ pad_off,
                               int* __restrict__ cursor, int* __restrict__ rowof,
                               int* __restrict__ perm) {
  const int n = blockIdx.x*blockDim.x + threadIdx.x;
  if (n >= N_TOK) return;
  const int e = gate_idx[n];
  const int pos = atomicAdd(&cursor[e], 1);
  const int row = pad_off[e] + pos;
  rowof[n] = row;
  perm[row] = n;
}

__global__ void gatherconv_kernel(const float* __restrict__ h, const int* __restrict__ rowof,
                                  u16* __restrict__ Hg) {
  const int n = blockIdx.x, t = threadIdx.x;
  const int row = rowof[n];
  float4 v = ((const float4*)h)[(size_t)n*(H_DIM/4) + t];
  uint2 pk; pk.x = pack2(v.x, v.y); pk.y = pack2(v.z, v.w);
  *(uint2*)&Hg[(size_t)row*H_DIM + t*4] = pk;
}

// -------- convert+transpose: in f32 [E*RPER][C] -> out bf16 [E][C][RPER] --------
template<int C, int RPER>
__global__ void ct_kernel(const float* __restrict__ in, u16* __restrict__ out) {
  __shared__ float tile[64][65];
  const int c0 = blockIdx.x*64, r0 = blockIdx.y*64;
  const int t = threadIdx.x;
  const int cq = t & 15, rr = t >> 4;
  #pragma unroll
  for (int p = 0; p < 4; ++p) {
    const int row = p*16 + rr;
    float4 v = ((const float4*)(in + (size_t)(r0+row)*C + c0))[cq];
    tile[row][cq*4+0] = v.x; tile[row][cq*4+1] = v.y;
    tile[row][cq*4+2] = v.z; tile[row][cq*4+3] = v.w;
  }
  __syncthreads();
  const int slot = t & 7, nn = t >> 3;
  const int e = r0 / RPER, rl0 = r0 % RPER;
  u16* outE = out + (size_t)e*C*RPER;
  #pragma unroll
  for (int p = 0; p < 2; ++p) {
    const int nc = p*32 + nn;
    uint4 q;
    q.x = pack2(tile[slot*8+0][nc], tile[slot*8+1][nc]);
    q.y = pack2(tile[slot*8+2][nc], tile[slot*8+3][nc]);
    q.z = pack2(tile[slot*8+4][nc], tile[slot*8+5][nc]);
    q.w = pack2(tile[slot*8+6][nc], tile[slot*8+7][nc]);
    *(uint4*)&outE[(size_t)(c0+nc)*RPER + rl0 + slot*8] = q;
  }
}

// -------- grouped MFMA GEMM: D[m][n] = sum_k A[e][m][k]*B[row n][k] --------
// A = transposed weights (bf16, k-contig). B = token rows (bf16, k-contig).
// EPI 1: out_bf = relu(D + b1[e][m]) as bf16 at [token_row][F_DIM] (H1)
// EPI 2: out_f[tok][m] = (D + b2[e][m]) * gate(tok), scattered via perm
template<int KTOT, int EPI>
__launch_bounds__(256, 2)
__global__ void gemm_kernel(const u16* __restrict__ A, const u16* __restrict__ B,
                            const float* __restrict__ bias,
                            const float* __restrict__ gate_val,
                            const int* __restrict__ perm,
                            const int* __restrict__ pad_off,
                            const int* __restrict__ cnt,
                            u16* __restrict__ out_bf, float* __restrict__ out_f) {
  constexpr int MD = (EPI == 1) ? F_DIM : H_DIM;
  const int e = blockIdx.z;
  const int seg0 = pad_off[e], seg1 = pad_off[e+1];
  if ((int)blockIdx.y*128 >= seg1 - seg0) return;
  const int t0 = seg0 + blockIdx.y*128;
  const int f0 = blockIdx.x*128;
  const u16* Ae = A + (size_t)e*MD*KTOT;

  __shared__ u16 As[128*64];
  __shared__ u16 Bs[128*64];

  const int tid = threadIdx.x;
  const int lane = tid & 63, wave = tid >> 6;
  const int wm = wave >> 1, wn = wave & 1;

  f32x4 acc[4][4];
  #pragma unroll
  for (int i = 0; i < 4; ++i)
    #pragma unroll
    for (int j = 0; j < 4; ++j) acc[i][j] = (f32x4){0.f, 0.f, 0.f, 0.f};

  const int rsub = lane >> 3, slot = lane & 7;
  const int csw = slot ^ rsub;              // swizzled source k-chunk
  const int fr = lane & 15, fg = lane >> 4;

  for (int kk = 0; kk < KTOT; kk += 64) {
    __syncthreads();
    #pragma unroll
    for (int i = 0; i < 4; ++i) {
      const int chunk = wave*4 + i;          // 16 chunks of 8 rows x 128B
      const int r = chunk*8 + rsub;
      gld_lds16(&As[chunk*512], Ae + (size_t)(f0 + r)*KTOT + kk + csw*8);
      gld_lds16(&Bs[chunk*512], B  + (size_t)(t0 + r)*KTOT + kk + csw*8);
    }
    __syncthreads();
    #pragma unroll
    for (int kh = 0; kh < 2; ++kh) {
      bf16x8 av[4], bv[4];
      #pragma unroll
      for (int mi = 0; mi < 4; ++mi) {
        const int ra = wm*64 + mi*16 + fr;
        const int sa = (kh*4 + fg) ^ (ra & 7);
        av[mi] = *(const bf16x8*)&As[ra*64 + sa*8];
      }
      #pragma unroll
      for (int ni = 0; ni < 4; ++ni) {
        const int rb = wn*64 + ni*16 + fr;
        const int sb = (kh*4 + fg) ^ (rb & 7);
        bv[ni] = *(const bf16x8*)&Bs[rb*64 + sb*8];
      }
      #pragma unroll
      for (int mi = 0; mi < 4; ++mi)
        #pragma unroll
        for (int ni = 0; ni < 4; ++ni)
          acc[mi][ni] = __builtin_amdgcn_mfma_f32_16x16x32_bf16(av[mi], bv[ni], acc[mi][ni], 0, 0, 0);
    }
  }

  // epilogue: C/D layout col = lane&15 (=n), row = (lane>>4)*4 + reg (=m)
  #pragma unroll
  for (int mi = 0; mi < 4; ++mi) {
    const int gm0 = f0 + wm*64 + mi*16 + fg*4;
    #pragma unroll
    for (int ni = 0; ni < 4; ++ni) {
      const int gn = wn*64 + ni*16 + fr;
      if constexpr (EPI == 1) {
        const float* bp = bias + (size_t)e*MD + gm0;
        const float v0 = fmaxf(acc[mi][ni][0] + bp[0], 0.f);
        const float v1 = fmaxf(acc[mi][ni][1] + bp[1], 0.f);
        const float v2 = fmaxf(acc[mi][ni][2] + bp[2], 0.f);
        const float v3 = fmaxf(acc[mi][ni][3] + bp[3], 0.f);
        uint2 pk; pk.x = pack2(v0, v1); pk.y = pack2(v2, v3);
        *(uint2*)&out_bf[(size_t)(t0 + gn)*F_DIM + gm0] = pk;
      } else {
        const int local = blockIdx.y*128 + gn;
        if (local < cnt[e]) {
          const int tok = perm[t0 + gn];
          const float g = gate_val[tok];
          const float* bp = bias + (size_t)e*MD + gm0;
          f32x4 v;
          v[0] = (acc[mi][ni][0] + bp[0]) * g;
          v[1] = (acc[mi][ni][1] + bp[1]) * g;
          v[2] = (acc[mi][ni][2] + bp[2]) * g;
          v[3] = (acc[mi][ni][3] + bp[3]) * g;
          *(f32x4*)&out_f[(size_t)tok*H_DIM + gm0] = v;
        }
      }
    }
  }
}

// ---------------- final: log_softmax(moe @ Wfc + bfc) ----------------
__global__ void final_kernel(const float* __restrict__ moe, const float* __restrict__ Wfc,
                             const float* __restrict__ bfc, float* __restrict__ out) {
  const int n = blockIdx.x, l = threadIdx.x;    // 64 threads
  const float4* m4 = (const float4*)(moe + (size_t)n*H_DIM);
  const float2* w2 = (const float2*)Wfc;
  float a0 = 0.f, a1 = 0.f;
  #pragma unroll
  for (int j = 0; j < H_DIM/256; ++j) {
    const int i4 = j*64 + l;
    const float4 v = m4[i4];
    const int hh = i4*4;
    const float2 q0 = w2[hh], q1 = w2[hh+1], q2 = w2[hh+2], q3 = w2[hh+3];
    a0 += v.x*q0.x + v.y*q1.x + v.z*q2.x + v.w*q3.x;
    a1 += v.x*q0.y + v.y*q1.y + v.z*q2.y + v.w*q3.y;
  }
  #pragma unroll
  for (int m = 32; m >= 1; m >>= 1) { a0 += __shfl_xor(a0, m); a1 += __shfl_xor(a1, m); }
  if (l == 0) {
    const float l0 = a0 + bfc[0], l1 = a1 + bfc[1];
    const float mx = fmaxf(l0, l1);
    const float lse = mx + logf(expf(l0 - mx) + expf(l1 - mx));
    out[(size_t)n*2 + 0] = l0 - lse;
    out[(size_t)n*2 + 1] = l1 - lse;
  }
}

extern "C" void kernel_launch(void* const* d_in, const int* in_sizes, int n_in,
                              void* d_out, int out_size, void* d_ws, size_t ws_size,
                              hipStream_t stream) {
  const int*   x   = (const int*)  d_in[0];
  const float* emb = (const float*)d_in[1];
  const float* Wg  = (const float*)d_in[2];
  const float* W1  = (const float*)d_in[3];
  const float* b1  = (const float*)d_in[4];
  const float* W2  = (const float*)d_in[5];
  const float* b2  = (const float*)d_in[6];
  const float* Wfc = (const float*)d_in[7];
  const float* bfc = (const float*)d_in[8];
  float* out = (float*)d_out;

  char* p = (char*)d_ws;
  size_t off = 0;
  auto alloc = [&](size_t bytes) {
    void* r = p + off;
    off = (off + bytes + 255) & ~(size_t)255;
    return r;
  };
  float* h        = (float*)alloc((size_t)N_TOK*H_DIM*4);
  float* moe      = (float*)alloc((size_t)N_TOK*H_DIM*4);
  float* gate_val = (float*)alloc((size_t)N_TOK*4);
  int*   gate_idx = (int*)  alloc((size_t)N_TOK*4);
  int*   rowof    = (int*)  alloc((size_t)N_TOK*4);
  int*   perm     = (int*)  alloc((size_t)NPAD*4);
  int*   meta     = (int*)  alloc(256);
  int* cnt = meta; int* cursor = meta + 8; int* pad_off = meta + 16;  // 9 used
  u16* Hg  = (u16*)alloc((size_t)NPAD*H_DIM*2);
  u16* H1  = (u16*)alloc((size_t)NPAD*F_DIM*2);
  u16* W1T = (u16*)alloc((size_t)E_NUM*F_DIM*H_DIM*2);
  u16* W2T = (u16*)alloc((size_t)E_NUM*F_DIM*H_DIM*2);

  hipMemsetAsync(meta, 0, 256, stream);
  pool_kernel<<<N_TOK, 256, 0, stream>>>(x, emb, h);
  gate_kernel<<<N_TOK, 64, 0, stream>>>(h, Wg, gate_val, gate_idx, cnt);
  offsets_kernel<<<1, 1, 0, stream>>>(cnt, pad_off);
  scatter_kernel<<<N_TOK/256, 256, 0, stream>>>(gate_idx, pad_off, cursor, rowof, perm);
  gatherconv_kernel<<<N_TOK, 256, 0, stream>>>(h, rowof, Hg);
  ct_kernel<F_DIM, H_DIM><<<dim3(F_DIM/64, E_NUM*H_DIM/64), 256, 0, stream>>>(W1, W1T);
  ct_kernel<H_DIM, F_DIM><<<dim3(H_DIM/64, E_NUM*F_DIM/64), 256, 0, stream>>>(W2, W2T);
  gemm_kernel<H_DIM, 1><<<dim3(F_DIM/128, 32, E_NUM), 256, 0, stream>>>(
      W1T, Hg, b1, nullptr, nullptr, pad_off, cnt, H1, nullptr);
  gemm_kernel<F_DIM, 2><<<dim3(H_DIM/128, 32, E_NUM), 256, 0, stream>>>(
      W2T, H1, b2, gate_val, perm, pad_off, cnt, nullptr, moe);
  final_kernel<<<N_TOK, 64, 0, stream>>>(moe, Wfc, bfc, out);
}

// Round 4
// 853.792 us; speedup vs baseline: 1.1469x; 1.1469x over previous
//
#include <hip/hip_runtime.h>
#include <stdint.h>

#define V_SZ 50000
#define H_DIM 1024
#define F_DIM 4096
#define E_NUM 8
#define S_LEN 128
#define N_TOK 4096
#define NPAD (N_TOK + E_NUM*128)

typedef unsigned short u16;
typedef unsigned int u32;
typedef short bf16x8 __attribute__((ext_vector_type(8)));
typedef float f32x4 __attribute__((ext_vector_type(4)));

__device__ __forceinline__ u16 f2bf(float f) {
  u32 u = __builtin_bit_cast(u32, f);
  u += 0x7fffu + ((u >> 16) & 1u);   // RNE; inputs finite
  return (u16)(u >> 16);
}
__device__ __forceinline__ u32 pack2(float a, float b) {
  return (u32)f2bf(a) | ((u32)f2bf(b) << 16);
}
__device__ __forceinline__ float bfhi2f(u32 bits_hi) {   // bf16 in high half
  return __builtin_bit_cast(float, bits_hi & 0xffff0000u);
}
__device__ __forceinline__ float bflo2f(u32 bits_lo) {   // bf16 in low half
  return __builtin_bit_cast(float, bits_lo << 16);
}

// async global->LDS, 16B per lane; LDS dest must be wave-uniform base (HW adds lane*16)
__device__ __forceinline__ void gld_lds16(u16* lds, const u16* g) {
  __builtin_amdgcn_global_load_lds((const __attribute__((address_space(1))) void*)g,
                                   (__attribute__((address_space(3))) void*)lds,
                                   16, 0, 0);
}

// ---------------- emb f32 -> bf16 (halves gather volume; L3-resident 102MB) ----------------
__global__ void embconv_kernel(const float* __restrict__ emb, u16* __restrict__ embb) {
  const size_t total = (size_t)V_SZ*H_DIM/8;
  const size_t stride = (size_t)gridDim.x*blockDim.x;
  for (size_t i = (size_t)blockIdx.x*blockDim.x + threadIdx.x; i < total; i += stride) {
    const float4 a = ((const float4*)emb)[i*2];
    const float4 b = ((const float4*)emb)[i*2+1];
    uint4 q;
    q.x = pack2(a.x, a.y); q.y = pack2(a.z, a.w);
    q.z = pack2(b.x, b.y); q.w = pack2(b.z, b.w);
    ((uint4*)embb)[i] = q;
  }
}

// ---------------- fused pool (bf16 gather) + top-1 gate ----------------
__global__ void poolgate_kernel(const int* __restrict__ x, const u16* __restrict__ embb,
                                const float* __restrict__ Wg,
                                u16* __restrict__ hB, float* __restrict__ gate_val,
                                int* __restrict__ gate_idx, int* __restrict__ cnt) {
  __shared__ int sidx[S_LEN];
  __shared__ float wsum[4][8];
  const int n = blockIdx.x, t = threadIdx.x;   // 256 threads, 4 h-elems each
  if (t < S_LEN) sidx[t] = x[n*S_LEN + t];
  __syncthreads();
  float a0 = 0.f, a1 = 0.f, a2 = 0.f, a3 = 0.f;
  #pragma unroll 8
  for (int s = 0; s < S_LEN; ++s) {
    const uint2 v = *(const uint2*)(embb + (size_t)sidx[s]*H_DIM + t*4);
    a0 += bflo2f(v.x); a1 += bfhi2f(v.x);
    a2 += bflo2f(v.y); a3 += bfhi2f(v.y);
  }
  const float sc = 1.0f/(float)S_LEN;
  a0 *= sc; a1 *= sc; a2 *= sc; a3 *= sc;
  // write h as bf16
  uint2 pk; pk.x = pack2(a0, a1); pk.y = pack2(a2, a3);
  *(uint2*)&hB[(size_t)n*H_DIM + t*4] = pk;
  // gate logits: this thread's 4 h-elems x Wg rows
  float lg[E_NUM];
  #pragma unroll
  for (int e = 0; e < E_NUM; ++e) lg[e] = 0.f;
  const float hv[4] = {a0, a1, a2, a3};
  #pragma unroll
  for (int j = 0; j < 4; ++j) {
    const float4* w4 = (const float4*)(Wg + (size_t)(t*4+j)*E_NUM);
    const float4 wa = w4[0], wb = w4[1];
    lg[0] += hv[j]*wa.x; lg[1] += hv[j]*wa.y; lg[2] += hv[j]*wa.z; lg[3] += hv[j]*wa.w;
    lg[4] += hv[j]*wb.x; lg[5] += hv[j]*wb.y; lg[6] += hv[j]*wb.z; lg[7] += hv[j]*wb.w;
  }
  #pragma unroll
  for (int m = 32; m >= 1; m >>= 1) {
    #pragma unroll
    for (int e = 0; e < E_NUM; ++e) lg[e] += __shfl_xor(lg[e], m);
  }
  if ((t & 63) == 0) {
    #pragma unroll
    for (int e = 0; e < E_NUM; ++e) wsum[t >> 6][e] = lg[e];
  }
  __syncthreads();
  if (t == 0) {
    float l[E_NUM];
    #pragma unroll
    for (int e = 0; e < E_NUM; ++e)
      l[e] = wsum[0][e] + wsum[1][e] + wsum[2][e] + wsum[3][e];
    float mx = l[0]; int im = 0;
    #pragma unroll
    for (int e = 1; e < E_NUM; ++e) if (l[e] > mx) { mx = l[e]; im = e; }
    float s = 0.f;
    #pragma unroll
    for (int e = 0; e < E_NUM; ++e) s += expf(l[e] - mx);
    gate_val[n] = 1.0f / s;
    gate_idx[n] = im;
    atomicAdd(&cnt[im], 1);
  }
}

// ---------------- expert segment offsets (padded to 128) ----------------
__global__ void offsets_kernel(const int* __restrict__ cnt, int* __restrict__ pad_off) {
  int o = 0;
  for (int e = 0; e < E_NUM; ++e) {
    pad_off[e] = o;
    o += ((cnt[e] + 127) >> 7) << 7;
  }
  pad_off[E_NUM] = o;
}

// ---------------- fused scatter + permuted copy into expert-grouped Hg ----------------
__global__ void scatterconv_kernel(const u16* __restrict__ hB, const int* __restrict__ gate_idx,
                                   const int* __restrict__ pad_off, int* __restrict__ cursor,
                                   int* __restrict__ perm, u16* __restrict__ Hg) {
  __shared__ int srow;
  const int n = blockIdx.x, t = threadIdx.x;   // 128 threads
  if (t == 0) {
    const int e = gate_idx[n];
    const int pos = atomicAdd(&cursor[e], 1);
    const int row = pad_off[e] + pos;
    perm[row] = n;
    srow = row;
  }
  __syncthreads();
  const int row = srow;
  const uint4 v = *(const uint4*)(hB + (size_t)n*H_DIM + t*8);
  *(uint4*)&Hg[(size_t)row*H_DIM + t*8] = v;
}

// -------- convert+transpose: in f32 [E*RPER][C] -> out bf16 [E][C][RPER] --------
template<int C, int RPER>
__global__ void ct_kernel(const float* __restrict__ in, u16* __restrict__ out) {
  __shared__ float tile[64][65];
  const int c0 = blockIdx.x*64, r0 = blockIdx.y*64;
  const int t = threadIdx.x;
  const int cq = t & 15, rr = t >> 4;
  #pragma unroll
  for (int p = 0; p < 4; ++p) {
    const int row = p*16 + rr;
    float4 v = ((const float4*)(in + (size_t)(r0+row)*C + c0))[cq];
    tile[row][cq*4+0] = v.x; tile[row][cq*4+1] = v.y;
    tile[row][cq*4+2] = v.z; tile[row][cq*4+3] = v.w;
  }
  __syncthreads();
  const int slot = t & 7, nn = t >> 3;
  const int e = r0 / RPER, rl0 = r0 % RPER;
  u16* outE = out + (size_t)e*C*RPER;
  #pragma unroll
  for (int p = 0; p < 2; ++p) {
    const int nc = p*32 + nn;
    uint4 q;
    q.x = pack2(tile[slot*8+0][nc], tile[slot*8+1][nc]);
    q.y = pack2(tile[slot*8+2][nc], tile[slot*8+3][nc]);
    q.z = pack2(tile[slot*8+4][nc], tile[slot*8+5][nc]);
    q.w = pack2(tile[slot*8+6][nc], tile[slot*8+7][nc]);
    *(uint4*)&outE[(size_t)(c0+nc)*RPER + rl0 + slot*8] = q;
  }
}

// -------- grouped MFMA GEMM: D[m][n] = sum_k A[e][m][k]*B[row n][k] --------
template<int KTOT, int EPI>
__launch_bounds__(256, 2)
__global__ void gemm_kernel(const u16* __restrict__ A, const u16* __restrict__ B,
                            const float* __restrict__ bias,
                            const float* __restrict__ gate_val,
                            const int* __restrict__ perm,
                            const int* __restrict__ pad_off,
                            const int* __restrict__ cnt,
                            u16* __restrict__ out_bf, float* __restrict__ out_f) {
  constexpr int MD = (EPI == 1) ? F_DIM : H_DIM;
  const int e = blockIdx.z;
  const int seg0 = pad_off[e], seg1 = pad_off[e+1];
  if ((int)blockIdx.y*128 >= seg1 - seg0) return;
  const int t0 = seg0 + blockIdx.y*128;
  const int f0 = blockIdx.x*128;
  const u16* Ae = A + (size_t)e*MD*KTOT;

  __shared__ u16 As[128*64];
  __shared__ u16 Bs[128*64];

  const int tid = threadIdx.x;
  const int lane = tid & 63, wave = tid >> 6;
  const int wm = wave >> 1, wn = wave & 1;

  f32x4 acc[4][4];
  #pragma unroll
  for (int i = 0; i < 4; ++i)
    #pragma unroll
    for (int j = 0; j < 4; ++j) acc[i][j] = (f32x4){0.f, 0.f, 0.f, 0.f};

  const int rsub = lane >> 3, slot = lane & 7;
  const int csw = slot ^ rsub;              // swizzled source k-chunk
  const int fr = lane & 15, fg = lane >> 4;

  for (int kk = 0; kk < KTOT; kk += 64) {
    __syncthreads();
    #pragma unroll
    for (int i = 0; i < 4; ++i) {
      const int chunk = wave*4 + i;          // 16 chunks of 8 rows x 128B
      const int r = chunk*8 + rsub;
      gld_lds16(&As[chunk*512], Ae + (size_t)(f0 + r)*KTOT + kk + csw*8);
      gld_lds16(&Bs[chunk*512], B  + (size_t)(t0 + r)*KTOT + kk + csw*8);
    }
    __syncthreads();
    #pragma unroll
    for (int kh = 0; kh < 2; ++kh) {
      bf16x8 av[4], bv[4];
      #pragma unroll
      for (int mi = 0; mi < 4; ++mi) {
        const int ra = wm*64 + mi*16 + fr;
        const int sa = (kh*4 + fg) ^ (ra & 7);
        av[mi] = *(const bf16x8*)&As[ra*64 + sa*8];
      }
      #pragma unroll
      for (int ni = 0; ni < 4; ++ni) {
        const int rb = wn*64 + ni*16 + fr;
        const int sb = (kh*4 + fg) ^ (rb & 7);
        bv[ni] = *(const bf16x8*)&Bs[rb*64 + sb*8];
      }
      #pragma unroll
      for (int mi = 0; mi < 4; ++mi)
        #pragma unroll
        for (int ni = 0; ni < 4; ++ni)
          acc[mi][ni] = __builtin_amdgcn_mfma_f32_16x16x32_bf16(av[mi], bv[ni], acc[mi][ni], 0, 0, 0);
    }
  }

  // epilogue: C/D layout col = lane&15 (=n), row = (lane>>4)*4 + reg (=m)
  #pragma unroll
  for (int mi = 0; mi < 4; ++mi) {
    const int gm0 = f0 + wm*64 + mi*16 + fg*4;
    #pragma unroll
    for (int ni = 0; ni < 4; ++ni) {
      const int gn = wn*64 + ni*16 + fr;
      if constexpr (EPI == 1) {
        const float* bp = bias + (size_t)e*MD + gm0;
        const float v0 = fmaxf(acc[mi][ni][0] + bp[0], 0.f);
        const float v1 = fmaxf(acc[mi][ni][1] + bp[1], 0.f);
        const float v2 = fmaxf(acc[mi][ni][2] + bp[2], 0.f);
        const float v3 = fmaxf(acc[mi][ni][3] + bp[3], 0.f);
        uint2 pk; pk.x = pack2(v0, v1); pk.y = pack2(v2, v3);
        *(uint2*)&out_bf[(size_t)(t0 + gn)*F_DIM + gm0] = pk;
      } else {
        const int local = blockIdx.y*128 + gn;
        if (local < cnt[e]) {
          const int tok = perm[t0 + gn];
          const float g = gate_val[tok];
          const float* bp = bias + (size_t)e*MD + gm0;
          f32x4 v;
          v[0] = (acc[mi][ni][0] + bp[0]) * g;
          v[1] = (acc[mi][ni][1] + bp[1]) * g;
          v[2] = (acc[mi][ni][2] + bp[2]) * g;
          v[3] = (acc[mi][ni][3] + bp[3]) * g;
          *(f32x4*)&out_f[(size_t)tok*H_DIM + gm0] = v;
        }
      }
    }
  }
}

// ---------------- final: log_softmax(moe @ Wfc + bfc) ----------------
__global__ void final_kernel(const float* __restrict__ moe, const float* __restrict__ Wfc,
                             const float* __restrict__ bfc, float* __restrict__ out) {
  const int n = blockIdx.x, l = threadIdx.x;    // 64 threads
  const float4* m4 = (const float4*)(moe + (size_t)n*H_DIM);
  const float2* w2 = (const float2*)Wfc;
  float a0 = 0.f, a1 = 0.f;
  #pragma unroll
  for (int j = 0; j < H_DIM/256; ++j) {
    const int i4 = j*64 + l;
    const float4 v = m4[i4];
    const int hh = i4*4;
    const float2 q0 = w2[hh], q1 = w2[hh+1], q2 = w2[hh+2], q3 = w2[hh+3];
    a0 += v.x*q0.x + v.y*q1.x + v.z*q2.x + v.w*q3.x;
    a1 += v.x*q0.y + v.y*q1.y + v.z*q2.y + v.w*q3.y;
  }
  #pragma unroll
  for (int m = 32; m >= 1; m >>= 1) { a0 += __shfl_xor(a0, m); a1 += __shfl_xor(a1, m); }
  if (l == 0) {
    const float l0 = a0 + bfc[0], l1 = a1 + bfc[1];
    const float mx = fmaxf(l0, l1);
    const float lse = mx + logf(expf(l0 - mx) + expf(l1 - mx));
    out[(size_t)n*2 + 0] = l0 - lse;
    out[(size_t)n*2 + 1] = l1 - lse;
  }
}

extern "C" void kernel_launch(void* const* d_in, const int* in_sizes, int n_in,
                              void* d_out, int out_size, void* d_ws, size_t ws_size,
                              hipStream_t stream) {
  const int*   x   = (const int*)  d_in[0];
  const float* emb = (const float*)d_in[1];
  const float* Wg  = (const float*)d_in[2];
  const float* W1  = (const float*)d_in[3];
  const float* b1  = (const float*)d_in[4];
  const float* W2  = (const float*)d_in[5];
  const float* b2  = (const float*)d_in[6];
  const float* Wfc = (const float*)d_in[7];
  const float* bfc = (const float*)d_in[8];
  float* out = (float*)d_out;

  char* p = (char*)d_ws;
  size_t off = 0;
  auto alloc = [&](size_t bytes) {
    void* r = p + off;
    off = (off + bytes + 255) & ~(size_t)255;
    return r;
  };
  u16*   hB       = (u16*)  alloc((size_t)N_TOK*H_DIM*2);
  float* moe      = (float*)alloc((size_t)N_TOK*H_DIM*4);
  float* gate_val = (float*)alloc((size_t)N_TOK*4);
  int*   gate_idx = (int*)  alloc((size_t)N_TOK*4);
  int*   perm     = (int*)  alloc((size_t)NPAD*4);
  int*   meta     = (int*)  alloc(256);
  int* cnt = meta; int* cursor = meta + 8; int* pad_off = meta + 16;  // 9 used
  u16* Hg  = (u16*)alloc((size_t)NPAD*H_DIM*2);
  u16* H1  = (u16*)alloc((size_t)NPAD*F_DIM*2);
  // union region: embb (102.4MB) is dead before ct writes W1T/W2T (134.2MB) — stream-ordered
  char* uni = (char*)alloc((size_t)E_NUM*F_DIM*H_DIM*2*2);
  u16* embb = (u16*)uni;
  u16* W1T  = (u16*)uni;
  u16* W2T  = W1T + (size_t)E_NUM*F_DIM*H_DIM;

  hipMemsetAsync(meta, 0, 256, stream);
  embconv_kernel<<<4096, 256, 0, stream>>>(emb, embb);
  poolgate_kernel<<<N_TOK, 256, 0, stream>>>(x, embb, Wg, hB, gate_val, gate_idx, cnt);
  offsets_kernel<<<1, 1, 0, stream>>>(cnt, pad_off);
  scatterconv_kernel<<<N_TOK, 128, 0, stream>>>(hB, gate_idx, pad_off, cursor, perm, Hg);
  ct_kernel<F_DIM, H_DIM><<<dim3(F_DIM/64, E_NUM*H_DIM/64), 256, 0, stream>>>(W1, W1T);
  ct_kernel<H_DIM, F_DIM><<<dim3(H_DIM/64, E_NUM*F_DIM/64), 256, 0, stream>>>(W2, W2T);
  gemm_kernel<H_DIM, 1><<<dim3(F_DIM/128, 32, E_NUM), 256, 0, stream>>>(
      W1T, Hg, b1, nullptr, nullptr, pad_off, cnt, H1, nullptr);
  gemm_kernel<F_DIM, 2><<<dim3(H_DIM/128, 32, E_NUM), 256, 0, stream>>>(
      W2T, H1, b2, gate_val, perm, pad_off, cnt, nullptr, moe);
  final_kernel<<<N_TOK, 64, 0, stream>>>(moe, Wfc, bfc, out);
}

// Round 6
// 805.452 us; speedup vs baseline: 1.2158x; 1.0600x over previous
//
#include <hip/hip_runtime.h>
#include <stdint.h>

#define V_SZ 50000
#define H_DIM 1024
#define F_DIM 4096
#define E_NUM 8
#define S_LEN 128
#define N_TOK 4096
#define NPAD (N_TOK + E_NUM*128)
#define EMB_SCALE 16.0f

typedef unsigned short u16;
typedef unsigned int u32;
typedef unsigned char u8;
typedef short bf16x8 __attribute__((ext_vector_type(8)));
typedef float f32x4 __attribute__((ext_vector_type(4)));
typedef float f32x2 __attribute__((ext_vector_type(2)));

__device__ __forceinline__ u16 f2bf(float f) {
  u32 u = __builtin_bit_cast(u32, f);
  u += 0x7fffu + ((u >> 16) & 1u);   // RNE; inputs finite
  return (u16)(u >> 16);
}
__device__ __forceinline__ u32 pack2(float a, float b) {
  return (u32)f2bf(a) | ((u32)f2bf(b) << 16);
}

// async global->LDS, 16B per lane; LDS dest must be wave-uniform base (HW adds lane*16)
__device__ __forceinline__ void gld_lds16(u16* lds, const u16* g) {
  __builtin_amdgcn_global_load_lds((const __attribute__((address_space(1))) void*)g,
                                   (__attribute__((address_space(3))) void*)lds,
                                   16, 0, 0);
}

// ---------------- emb f32 -> fp8 e4m3 (x16 scale; 51MB table, L3-resident) ----------------
__global__ void embconv_kernel(const float* __restrict__ emb, u8* __restrict__ embf8) {
  const size_t total = (size_t)V_SZ*H_DIM/8;
  const size_t stride = (size_t)gridDim.x*blockDim.x;
  for (size_t i = (size_t)blockIdx.x*blockDim.x + threadIdx.x; i < total; i += stride) {
    const float4 a = ((const float4*)emb)[i*2];
    const float4 b = ((const float4*)emb)[i*2+1];
    u32 w0, w1;
    w0 = __builtin_amdgcn_cvt_pk_fp8_f32(a.x*EMB_SCALE, a.y*EMB_SCALE, 0u, false);
    w0 = __builtin_amdgcn_cvt_pk_fp8_f32(a.z*EMB_SCALE, a.w*EMB_SCALE, w0, true);
    w1 = __builtin_amdgcn_cvt_pk_fp8_f32(b.x*EMB_SCALE, b.y*EMB_SCALE, 0u, false);
    w1 = __builtin_amdgcn_cvt_pk_fp8_f32(b.z*EMB_SCALE, b.w*EMB_SCALE, w1, true);
    ((uint2*)embf8)[i] = make_uint2(w0, w1);
  }
}

// ---------------- fused pool (fp8 gather) + top-1 gate ----------------
__global__ void poolgate_kernel(const int* __restrict__ x, const u8* __restrict__ embf8,
                                const float* __restrict__ Wg,
                                u16* __restrict__ hB, float* __restrict__ gate_val,
                                int* __restrict__ gate_idx, int* __restrict__ cnt) {
  __shared__ int sidx[S_LEN];
  __shared__ float wsum[4][8];
  const int n = blockIdx.x, t = threadIdx.x;   // 256 threads, 4 h-elems each
  if (t < S_LEN) sidx[t] = x[n*S_LEN + t];
  __syncthreads();
  float a0 = 0.f, a1 = 0.f, a2 = 0.f, a3 = 0.f;
  #pragma unroll 8
  for (int s = 0; s < S_LEN; ++s) {
    const u32 w = *(const u32*)(embf8 + (size_t)sidx[s]*H_DIM + t*4);
    const f32x2 lo = __builtin_amdgcn_cvt_pk_f32_fp8(w, false);
    const f32x2 hi = __builtin_amdgcn_cvt_pk_f32_fp8(w, true);
    a0 += lo[0]; a1 += lo[1]; a2 += hi[0]; a3 += hi[1];
  }
  const float sc = 1.0f/((float)S_LEN * EMB_SCALE);
  a0 *= sc; a1 *= sc; a2 *= sc; a3 *= sc;
  // write h as bf16
  uint2 pk; pk.x = pack2(a0, a1); pk.y = pack2(a2, a3);
  *(uint2*)&hB[(size_t)n*H_DIM + t*4] = pk;
  // gate logits: this thread's 4 h-elems x Wg rows
  float lg[E_NUM];
  #pragma unroll
  for (int e = 0; e < E_NUM; ++e) lg[e] = 0.f;
  const float hv[4] = {a0, a1, a2, a3};
  #pragma unroll
  for (int j = 0; j < 4; ++j) {
    const float4* w4 = (const float4*)(Wg + (size_t)(t*4+j)*E_NUM);
    const float4 wa = w4[0], wb = w4[1];
    lg[0] += hv[j]*wa.x; lg[1] += hv[j]*wa.y; lg[2] += hv[j]*wa.z; lg[3] += hv[j]*wa.w;
    lg[4] += hv[j]*wb.x; lg[5] += hv[j]*wb.y; lg[6] += hv[j]*wb.z; lg[7] += hv[j]*wb.w;
  }
  #pragma unroll
  for (int m = 32; m >= 1; m >>= 1) {
    #pragma unroll
    for (int e = 0; e < E_NUM; ++e) lg[e] += __shfl_xor(lg[e], m);
  }
  if ((t & 63) == 0) {
    #pragma unroll
    for (int e = 0; e < E_NUM; ++e) wsum[t >> 6][e] = lg[e];
  }
  __syncthreads();
  if (t == 0) {
    float l[E_NUM];
    #pragma unroll
    for (int e = 0; e < E_NUM; ++e)
      l[e] = wsum[0][e] + wsum[1][e] + wsum[2][e] + wsum[3][e];
    float mx = l[0]; int im = 0;
    #pragma unroll
    for (int e = 1; e < E_NUM; ++e) if (l[e] > mx) { mx = l[e]; im = e; }
    float s = 0.f;
    #pragma unroll
    for (int e = 0; e < E_NUM; ++e) s += expf(l[e] - mx);
    gate_val[n] = 1.0f / s;
    gate_idx[n] = im;
    atomicAdd(&cnt[im], 1);
  }
}

// ---------------- expert segment offsets (padded to 128) ----------------
__global__ void offsets_kernel(const int* __restrict__ cnt, int* __restrict__ pad_off) {
  int o = 0;
  for (int e = 0; e < E_NUM; ++e) {
    pad_off[e] = o;
    o += ((cnt[e] + 127) >> 7) << 7;
  }
  pad_off[E_NUM] = o;
}

// ---------------- fused scatter + permuted copy into expert-grouped Hg ----------------
__global__ void scatterconv_kernel(const u16* __restrict__ hB, const int* __restrict__ gate_idx,
                                   const int* __restrict__ pad_off, int* __restrict__ cursor,
                                   int* __restrict__ perm, u16* __restrict__ Hg) {
  __shared__ int srow;
  const int n = blockIdx.x, t = threadIdx.x;   // 128 threads
  if (t == 0) {
    const int e = gate_idx[n];
    const int pos = atomicAdd(&cursor[e], 1);
    const int row = pad_off[e] + pos;
    perm[row] = n;
    srow = row;
  }
  __syncthreads();
  const int row = srow;
  const uint4 v = *(const uint4*)(hB + (size_t)n*H_DIM + t*8);
  *(uint4*)&Hg[(size_t)row*H_DIM + t*8] = v;
}

// -------- convert+transpose: in f32 [E*RPER][C] -> out bf16 [E][C][RPER] --------
template<int C, int RPER>
__global__ void ct_kernel(const float* __restrict__ in, u16* __restrict__ out) {
  __shared__ float tile[64][65];
  const int c0 = blockIdx.x*64, r0 = blockIdx.y*64;
  const int t = threadIdx.x;
  const int cq = t & 15, rr = t >> 4;
  #pragma unroll
  for (int p = 0; p < 4; ++p) {
    const int row = p*16 + rr;
    float4 v = ((const float4*)(in + (size_t)(r0+row)*C + c0))[cq];
    tile[row][cq*4+0] = v.x; tile[row][cq*4+1] = v.y;
    tile[row][cq*4+2] = v.z; tile[row][cq*4+3] = v.w;
  }
  __syncthreads();
  const int slot = t & 7, nn = t >> 3;
  const int e = r0 / RPER, rl0 = r0 % RPER;
  u16* outE = out + (size_t)e*C*RPER;
  #pragma unroll
  for (int p = 0; p < 2; ++p) {
    const int nc = p*32 + nn;
    uint4 q;
    q.x = pack2(tile[slot*8+0][nc], tile[slot*8+1][nc]);
    q.y = pack2(tile[slot*8+2][nc], tile[slot*8+3][nc]);
    q.z = pack2(tile[slot*8+4][nc], tile[slot*8+5][nc]);
    q.w = pack2(tile[slot*8+6][nc], tile[slot*8+7][nc]);
    *(uint4*)&outE[(size_t)(c0+nc)*RPER + rl0 + slot*8] = q;
  }
}

// -------- grouped MFMA GEMM: D[m][n] = sum_k A[e][m][k]*B[row n][k] --------
template<int KTOT, int EPI>
__launch_bounds__(256, 2)
__global__ void gemm_kernel(const u16* __restrict__ A, const u16* __restrict__ B,
                            const float* __restrict__ bias,
                            const float* __restrict__ gate_val,
                            const int* __restrict__ perm,
                            const int* __restrict__ pad_off,
                            const int* __restrict__ cnt,
                            u16* __restrict__ out_bf, float* __restrict__ out_f) {
  constexpr int MD = (EPI == 1) ? F_DIM : H_DIM;
  const int e = blockIdx.z;
  const int seg0 = pad_off[e], seg1 = pad_off[e+1];
  if ((int)blockIdx.y*128 >= seg1 - seg0) return;
  const int t0 = seg0 + blockIdx.y*128;
  const int f0 = blockIdx.x*128;
  const u16* Ae = A + (size_t)e*MD*KTOT;

  __shared__ u16 As[128*64];
  __shared__ u16 Bs[128*64];

  const int tid = threadIdx.x;
  const int lane = tid & 63, wave = tid >> 6;
  const int wm = wave >> 1, wn = wave & 1;

  f32x4 acc[4][4];
  #pragma unroll
  for (int i = 0; i < 4; ++i)
    #pragma unroll
    for (int j = 0; j < 4; ++j) acc[i][j] = (f32x4){0.f, 0.f, 0.f, 0.f};

  const int rsub = lane >> 3, slot = lane & 7;
  const int csw = slot ^ rsub;              // swizzled source k-chunk
  const int fr = lane & 15, fg = lane >> 4;

  for (int kk = 0; kk < KTOT; kk += 64) {
    __syncthreads();
    #pragma unroll
    for (int i = 0; i < 4; ++i) {
      const int chunk = wave*4 + i;          // 16 chunks of 8 rows x 128B
      const int r = chunk*8 + rsub;
      gld_lds16(&As[chunk*512], Ae + (size_t)(f0 + r)*KTOT + kk + csw*8);
      gld_lds16(&Bs[chunk*512], B  + (size_t)(t0 + r)*KTOT + kk + csw*8);
    }
    __syncthreads();
    #pragma unroll
    for (int kh = 0; kh < 2; ++kh) {
      bf16x8 av[4], bv[4];
      #pragma unroll
      for (int mi = 0; mi < 4; ++mi) {
        const int ra = wm*64 + mi*16 + fr;
        const int sa = (kh*4 + fg) ^ (ra & 7);
        av[mi] = *(const bf16x8*)&As[ra*64 + sa*8];
      }
      #pragma unroll
      for (int ni = 0; ni < 4; ++ni) {
        const int rb = wn*64 + ni*16 + fr;
        const int sb = (kh*4 + fg) ^ (rb & 7);
        bv[ni] = *(const bf16x8*)&Bs[rb*64 + sb*8];
      }
      #pragma unroll
      for (int mi = 0; mi < 4; ++mi)
        #pragma unroll
        for (int ni = 0; ni < 4; ++ni)
          acc[mi][ni] = __builtin_amdgcn_mfma_f32_16x16x32_bf16(av[mi], bv[ni], acc[mi][ni], 0, 0, 0);
    }
  }

  // epilogue: C/D layout col = lane&15 (=n), row = (lane>>4)*4 + reg (=m)
  #pragma unroll
  for (int mi = 0; mi < 4; ++mi) {
    const int gm0 = f0 + wm*64 + mi*16 + fg*4;
    #pragma unroll
    for (int ni = 0; ni < 4; ++ni) {
      const int gn = wn*64 + ni*16 + fr;
      if constexpr (EPI == 1) {
        const float* bp = bias + (size_t)e*MD + gm0;
        const float v0 = fmaxf(acc[mi][ni][0] + bp[0], 0.f);
        const float v1 = fmaxf(acc[mi][ni][1] + bp[1], 0.f);
        const float v2 = fmaxf(acc[mi][ni][2] + bp[2], 0.f);
        const float v3 = fmaxf(acc[mi][ni][3] + bp[3], 0.f);
        uint2 pk; pk.x = pack2(v0, v1); pk.y = pack2(v2, v3);
        *(uint2*)&out_bf[(size_t)(t0 + gn)*F_DIM + gm0] = pk;
      } else {
        const int local = blockIdx.y*128 + gn;
        if (local < cnt[e]) {
          const int tok = perm[t0 + gn];
          const float g = gate_val[tok];
          const float* bp = bias + (size_t)e*MD + gm0;
          f32x4 v;
          v[0] = (acc[mi][ni][0] + bp[0]) * g;
          v[1] = (acc[mi][ni][1] + bp[1]) * g;
          v[2] = (acc[mi][ni][2] + bp[2]) * g;
          v[3] = (acc[mi][ni][3] + bp[3]) * g;
          *(f32x4*)&out_f[(size_t)tok*H_DIM + gm0] = v;
        }
      }
    }
  }
}

// ---------------- final: log_softmax(moe @ Wfc + bfc) ----------------
__global__ void final_kernel(const float* __restrict__ moe, const float* __restrict__ Wfc,
                             const float* __restrict__ bfc, float* __restrict__ out) {
  const int n = blockIdx.x, l = threadIdx.x;    // 64 threads
  const float4* m4 = (const float4*)(moe + (size_t)n*H_DIM);
  const float2* w2 = (const float2*)Wfc;
  float a0 = 0.f, a1 = 0.f;
  #pragma unroll
  for (int j = 0; j < H_DIM/256; ++j) {
    const int i4 = j*64 + l;
    const float4 v = m4[i4];
    const int hh = i4*4;
    const float2 q0 = w2[hh], q1 = w2[hh+1], q2 = w2[hh+2], q3 = w2[hh+3];
    a0 += v.x*q0.x + v.y*q1.x + v.z*q2.x + v.w*q3.x;
    a1 += v.x*q0.y + v.y*q1.y + v.z*q2.y + v.w*q3.y;
  }
  #pragma unroll
  for (int m = 32; m >= 1; m >>= 1) { a0 += __shfl_xor(a0, m); a1 += __shfl_xor(a1, m); }
  if (l == 0) {
    const float l0 = a0 + bfc[0], l1 = a1 + bfc[1];
    const float mx = fmaxf(l0, l1);
    const float lse = mx + logf(expf(l0 - mx) + expf(l1 - mx));
    out[(size_t)n*2 + 0] = l0 - lse;
    out[(size_t)n*2 + 1] = l1 - lse;
  }
}

extern "C" void kernel_launch(void* const* d_in, const int* in_sizes, int n_in,
                              void* d_out, int out_size, void* d_ws, size_t ws_size,
                              hipStream_t stream) {
  const int*   x   = (const int*)  d_in[0];
  const float* emb = (const float*)d_in[1];
  const float* Wg  = (const float*)d_in[2];
  const float* W1  = (const float*)d_in[3];
  const float* b1  = (const float*)d_in[4];
  const float* W2  = (const float*)d_in[5];
  const float* b2  = (const float*)d_in[6];
  const float* Wfc = (const float*)d_in[7];
  const float* bfc = (const float*)d_in[8];
  float* out = (float*)d_out;

  char* p = (char*)d_ws;
  size_t off = 0;
  auto alloc = [&](size_t bytes) {
    void* r = p + off;
    off = (off + bytes + 255) & ~(size_t)255;
    return r;
  };
  u16*   hB       = (u16*)  alloc((size_t)N_TOK*H_DIM*2);
  float* moe      = (float*)alloc((size_t)N_TOK*H_DIM*4);
  float* gate_val = (float*)alloc((size_t)N_TOK*4);
  int*   gate_idx = (int*)  alloc((size_t)N_TOK*4);
  int*   perm     = (int*)  alloc((size_t)NPAD*4);
  int*   meta     = (int*)  alloc(256);
  int* cnt = meta; int* cursor = meta + 8; int* pad_off = meta + 16;  // 9 used
  u16* Hg  = (u16*)alloc((size_t)NPAD*H_DIM*2);
  u16* H1  = (u16*)alloc((size_t)NPAD*F_DIM*2);
  // union region: embf8 (51.2MB) is dead before ct writes W1T/W2T (134.2MB) — stream-ordered
  char* uni = (char*)alloc((size_t)E_NUM*F_DIM*H_DIM*2*2);
  u8*  embf8 = (u8*)uni;
  u16* W1T   = (u16*)uni;
  u16* W2T   = W1T + (size_t)E_NUM*F_DIM*H_DIM;

  hipMemsetAsync(meta, 0, 256, stream);
  embconv_kernel<<<4096, 256, 0, stream>>>(emb, embf8);
  poolgate_kernel<<<N_TOK, 256, 0, stream>>>(x, embf8, Wg, hB, gate_val, gate_idx, cnt);
  offsets_kernel<<<1, 1, 0, stream>>>(cnt, pad_off);
  scatterconv_kernel<<<N_TOK, 128, 0, stream>>>(hB, gate_idx, pad_off, cursor, perm, Hg);
  ct_kernel<F_DIM, H_DIM><<<dim3(F_DIM/64, E_NUM*H_DIM/64), 256, 0, stream>>>(W1, W1T);
  ct_kernel<H_DIM, F_DIM><<<dim3(H_DIM/64, E_NUM*F_DIM/64), 256, 0, stream>>>(W2, W2T);
  gemm_kernel<H_DIM, 1><<<dim3(F_DIM/128, 32, E_NUM), 256, 0, stream>>>(
      W1T, Hg, b1, nullptr, nullptr, pad_off, cnt, H1, nullptr);
  gemm_kernel<F_DIM, 2><<<dim3(H_DIM/128, 32, E_NUM), 256, 0, stream>>>(
      W2T, H1, b2, gate_val, perm, pad_off, cnt, nullptr, moe);
  final_kernel<<<N_TOK, 64, 0, stream>>>(moe, Wfc, bfc, out);
}

// Round 9
// 756.618 us; speedup vs baseline: 1.2942x; 1.0645x over previous
//
#include <hip/hip_runtime.h>
#include <stdint.h>

#define V_SZ 50000
#define H_DIM 1024
#define F_DIM 4096
#define E_NUM 8
#define S_LEN 128
#define N_TOK 4096
#define NPAD (N_TOK + E_NUM*128)
#define EMB_SCALE 16.0f
#define SK2 4   // split-K factor for FFN2

typedef unsigned short u16;
typedef unsigned int u32;
typedef unsigned char u8;
typedef short bf16x8 __attribute__((ext_vector_type(8)));
typedef float f32x4 __attribute__((ext_vector_type(4)));
typedef float f32x2 __attribute__((ext_vector_type(2)));

__device__ __forceinline__ u16 f2bf(float f) {
  u32 u = __builtin_bit_cast(u32, f);
  u += 0x7fffu + ((u >> 16) & 1u);   // RNE; inputs finite
  return (u16)(u >> 16);
}
__device__ __forceinline__ u32 pack2(float a, float b) {
  return (u32)f2bf(a) | ((u32)f2bf(b) << 16);
}

// async global->LDS, 16B per lane; LDS dest must be wave-uniform base (HW adds lane*16)
__device__ __forceinline__ void gld_lds16(u16* lds, const u16* g) {
  __builtin_amdgcn_global_load_lds((const __attribute__((address_space(1))) void*)g,
                                   (__attribute__((address_space(3))) void*)lds,
                                   16, 0, 0);
}

// ---------------- emb f32 -> fp8 e4m3 (x16 scale; 51MB table, L3-resident) ----------------
__global__ void embconv_kernel(const float* __restrict__ emb, u8* __restrict__ embf8) {
  const size_t total = (size_t)V_SZ*H_DIM/8;
  const size_t stride = (size_t)gridDim.x*blockDim.x;
  for (size_t i = (size_t)blockIdx.x*blockDim.x + threadIdx.x; i < total; i += stride) {
    const float4 a = ((const float4*)emb)[i*2];
    const float4 b = ((const float4*)emb)[i*2+1];
    u32 w0, w1;
    w0 = __builtin_amdgcn_cvt_pk_fp8_f32(a.x*EMB_SCALE, a.y*EMB_SCALE, 0u, false);
    w0 = __builtin_amdgcn_cvt_pk_fp8_f32(a.z*EMB_SCALE, a.w*EMB_SCALE, w0, true);
    w1 = __builtin_amdgcn_cvt_pk_fp8_f32(b.x*EMB_SCALE, b.y*EMB_SCALE, 0u, false);
    w1 = __builtin_amdgcn_cvt_pk_fp8_f32(b.z*EMB_SCALE, b.w*EMB_SCALE, w1, true);
    ((uint2*)embf8)[i] = make_uint2(w0, w1);
  }
}

// ---------------- fused pool (fp8 gather) + top-1 gate ----------------
__global__ void poolgate_kernel(const int* __restrict__ x, const u8* __restrict__ embf8,
                                const float* __restrict__ Wg,
                                u16* __restrict__ hB, float* __restrict__ gate_val,
                                int* __restrict__ gate_idx, int* __restrict__ cnt) {
  __shared__ int sidx[S_LEN];
  __shared__ float wsum[4][8];
  const int n = blockIdx.x, t = threadIdx.x;   // 256 threads, 4 h-elems each
  if (t < S_LEN) sidx[t] = x[n*S_LEN + t];
  __syncthreads();
  float a0 = 0.f, a1 = 0.f, a2 = 0.f, a3 = 0.f;
  #pragma unroll 8
  for (int s = 0; s < S_LEN; ++s) {
    const u32 w = *(const u32*)(embf8 + (size_t)sidx[s]*H_DIM + t*4);
    const f32x2 lo = __builtin_amdgcn_cvt_pk_f32_fp8(w, false);
    const f32x2 hi = __builtin_amdgcn_cvt_pk_f32_fp8(w, true);
    a0 += lo[0]; a1 += lo[1]; a2 += hi[0]; a3 += hi[1];
  }
  const float sc = 1.0f/((float)S_LEN * EMB_SCALE);
  a0 *= sc; a1 *= sc; a2 *= sc; a3 *= sc;
  // write h as bf16
  uint2 pk; pk.x = pack2(a0, a1); pk.y = pack2(a2, a3);
  *(uint2*)&hB[(size_t)n*H_DIM + t*4] = pk;
  // gate logits: this thread's 4 h-elems x Wg rows
  float lg[E_NUM];
  #pragma unroll
  for (int e = 0; e < E_NUM; ++e) lg[e] = 0.f;
  const float hv[4] = {a0, a1, a2, a3};
  #pragma unroll
  for (int j = 0; j < 4; ++j) {
    const float4* w4 = (const float4*)(Wg + (size_t)(t*4+j)*E_NUM);
    const float4 wa = w4[0], wb = w4[1];
    lg[0] += hv[j]*wa.x; lg[1] += hv[j]*wa.y; lg[2] += hv[j]*wa.z; lg[3] += hv[j]*wa.w;
    lg[4] += hv[j]*wb.x; lg[5] += hv[j]*wb.y; lg[6] += hv[j]*wb.z; lg[7] += hv[j]*wb.w;
  }
  #pragma unroll
  for (int m = 32; m >= 1; m >>= 1) {
    #pragma unroll
    for (int e = 0; e < E_NUM; ++e) lg[e] += __shfl_xor(lg[e], m);
  }
  if ((t & 63) == 0) {
    #pragma unroll
    for (int e = 0; e < E_NUM; ++e) wsum[t >> 6][e] = lg[e];
  }
  __syncthreads();
  if (t == 0) {
    float l[E_NUM];
    #pragma unroll
    for (int e = 0; e < E_NUM; ++e)
      l[e] = wsum[0][e] + wsum[1][e] + wsum[2][e] + wsum[3][e];
    float mx = l[0]; int im = 0;
    #pragma unroll
    for (int e = 1; e < E_NUM; ++e) if (l[e] > mx) { mx = l[e]; im = e; }
    float s = 0.f;
    #pragma unroll
    for (int e = 0; e < E_NUM; ++e) s += expf(l[e] - mx);
    gate_val[n] = 1.0f / s;
    gate_idx[n] = im;
    atomicAdd(&cnt[im], 1);
  }
}

// ---------------- expert segment offsets (padded to 128) ----------------
__global__ void offsets_kernel(const int* __restrict__ cnt, int* __restrict__ pad_off) {
  int o = 0;
  for (int e = 0; e < E_NUM; ++e) {
    pad_off[e] = o;
    o += ((cnt[e] + 127) >> 7) << 7;
  }
  pad_off[E_NUM] = o;
}

// ---------------- fused scatter + permuted copy into expert-grouped Hg ----------------
__global__ void scatterconv_kernel(const u16* __restrict__ hB, const int* __restrict__ gate_idx,
                                   const int* __restrict__ pad_off, int* __restrict__ cursor,
                                   int* __restrict__ perm, u16* __restrict__ Hg) {
  __shared__ int srow;
  const int n = blockIdx.x, t = threadIdx.x;   // 128 threads
  if (t == 0) {
    const int e = gate_idx[n];
    const int pos = atomicAdd(&cursor[e], 1);
    const int row = pad_off[e] + pos;
    perm[row] = n;
    srow = row;
  }
  __syncthreads();
  const int row = srow;
  const uint4 v = *(const uint4*)(hB + (size_t)n*H_DIM + t*8);
  *(uint4*)&Hg[(size_t)row*H_DIM + t*8] = v;
}

// -------- convert+transpose: in f32 [E*RPER][C] -> out bf16 [E][C][RPER] --------
template<int C, int RPER>
__global__ void ct_kernel(const float* __restrict__ in, u16* __restrict__ out) {
  __shared__ float tile[64][65];
  const int c0 = blockIdx.x*64, r0 = blockIdx.y*64;
  const int t = threadIdx.x;
  const int cq = t & 15, rr = t >> 4;
  #pragma unroll
  for (int p = 0; p < 4; ++p) {
    const int row = p*16 + rr;
    float4 v = ((const float4*)(in + (size_t)(r0+row)*C + c0))[cq];
    tile[row][cq*4+0] = v.x; tile[row][cq*4+1] = v.y;
    tile[row][cq*4+2] = v.z; tile[row][cq*4+3] = v.w;
  }
  __syncthreads();
  const int slot = t & 7, nn = t >> 3;
  const int e = r0 / RPER, rl0 = r0 % RPER;
  u16* outE = out + (size_t)e*C*RPER;
  #pragma unroll
  for (int p = 0; p < 2; ++p) {
    const int nc = p*32 + nn;
    uint4 q;
    q.x = pack2(tile[slot*8+0][nc], tile[slot*8+1][nc]);
    q.y = pack2(tile[slot*8+2][nc], tile[slot*8+3][nc]);
    q.z = pack2(tile[slot*8+4][nc], tile[slot*8+5][nc]);
    q.w = pack2(tile[slot*8+6][nc], tile[slot*8+7][nc]);
    *(uint4*)&outE[(size_t)(c0+nc)*RPER + rl0 + slot*8] = q;
  }
}

// -------- grouped MFMA GEMM: D[m][n] = sum_k A[e][m][k]*B[row n][k] --------
// EPI 1: out_bf = relu(D + b1[e][m]) as bf16 at [token_row][F_DIM] (H1)
// EPI 2 (split-K SK): raw f32 partial planes out_f[kc][tok][m], scattered via perm;
//        bias/gate applied in final_kernel
template<int KTOT, int EPI, int SK>
__launch_bounds__(256, 2)
__global__ void gemm_kernel(const u16* __restrict__ A, const u16* __restrict__ B,
                            const float* __restrict__ bias,
                            const int* __restrict__ perm,
                            const int* __restrict__ pad_off,
                            const int* __restrict__ cnt,
                            u16* __restrict__ out_bf, float* __restrict__ out_f) {
  constexpr int MD = (EPI == 1) ? F_DIM : H_DIM;
  const int e  = blockIdx.z / SK;
  const int kc = blockIdx.z % SK;
  const int seg0 = pad_off[e], seg1 = pad_off[e+1];
  if ((int)blockIdx.y*128 >= seg1 - seg0) return;
  const int t0 = seg0 + blockIdx.y*128;
  const int f0 = blockIdx.x*128;
  const u16* Ae = A + (size_t)e*MD*KTOT;

  __shared__ u16 As[128*64];
  __shared__ u16 Bs[128*64];

  const int tid = threadIdx.x;
  const int lane = tid & 63, wave = tid >> 6;
  const int wm = wave >> 1, wn = wave & 1;

  f32x4 acc[4][4];
  #pragma unroll
  for (int i = 0; i < 4; ++i)
    #pragma unroll
    for (int j = 0; j < 4; ++j) acc[i][j] = (f32x4){0.f, 0.f, 0.f, 0.f};

  const int rsub = lane >> 3, slot = lane & 7;
  const int csw = slot ^ rsub;              // swizzled source k-chunk
  const int fr = lane & 15, fg = lane >> 4;

  const int kbeg = kc*(KTOT/SK), kend = kbeg + KTOT/SK;
  for (int kk = kbeg; kk < kend; kk += 64) {
    __syncthreads();
    #pragma unroll
    for (int i = 0; i < 4; ++i) {
      const int chunk = wave*4 + i;          // 16 chunks of 8 rows x 128B
      const int r = chunk*8 + rsub;
      gld_lds16(&As[chunk*512], Ae + (size_t)(f0 + r)*KTOT + kk + csw*8);
      gld_lds16(&Bs[chunk*512], B  + (size_t)(t0 + r)*KTOT + kk + csw*8);
    }
    __syncthreads();
    #pragma unroll
    for (int kh = 0; kh < 2; ++kh) {
      bf16x8 av[4], bv[4];
      #pragma unroll
      for (int mi = 0; mi < 4; ++mi) {
        const int ra = wm*64 + mi*16 + fr;
        const int sa = (kh*4 + fg) ^ (ra & 7);
        av[mi] = *(const bf16x8*)&As[ra*64 + sa*8];
      }
      #pragma unroll
      for (int ni = 0; ni < 4; ++ni) {
        const int rb = wn*64 + ni*16 + fr;
        const int sb = (kh*4 + fg) ^ (rb & 7);
        bv[ni] = *(const bf16x8*)&Bs[rb*64 + sb*8];
      }
      #pragma unroll
      for (int mi = 0; mi < 4; ++mi)
        #pragma unroll
        for (int ni = 0; ni < 4; ++ni)
          acc[mi][ni] = __builtin_amdgcn_mfma_f32_16x16x32_bf16(av[mi], bv[ni], acc[mi][ni], 0, 0, 0);
    }
  }

  // epilogue: C/D layout col = lane&15 (=n), row = (lane>>4)*4 + reg (=m)
  #pragma unroll
  for (int mi = 0; mi < 4; ++mi) {
    const int gm0 = f0 + wm*64 + mi*16 + fg*4;
    #pragma unroll
    for (int ni = 0; ni < 4; ++ni) {
      const int gn = wn*64 + ni*16 + fr;
      if constexpr (EPI == 1) {
        const float* bp = bias + (size_t)e*MD + gm0;
        const float v0 = fmaxf(acc[mi][ni][0] + bp[0], 0.f);
        const float v1 = fmaxf(acc[mi][ni][1] + bp[1], 0.f);
        const float v2 = fmaxf(acc[mi][ni][2] + bp[2], 0.f);
        const float v3 = fmaxf(acc[mi][ni][3] + bp[3], 0.f);
        uint2 pk; pk.x = pack2(v0, v1); pk.y = pack2(v2, v3);
        *(uint2*)&out_bf[(size_t)(t0 + gn)*F_DIM + gm0] = pk;
      } else {
        const int local = blockIdx.y*128 + gn;
        if (local < cnt[e]) {
          const int tok = perm[t0 + gn];
          float* plane = out_f + (size_t)kc*N_TOK*H_DIM;
          *(f32x4*)&plane[(size_t)tok*H_DIM + gm0] = acc[mi][ni];
        }
      }
    }
  }
}

// ---- final: reduce SK2 planes + bias + gate, then log_softmax((.)@Wfc + bfc) ----
__global__ void final_kernel(const float* __restrict__ planes,
                             const float* __restrict__ b2,
                             const int* __restrict__ gate_idx,
                             const float* __restrict__ gate_val,
                             const float* __restrict__ Wfc,
                             const float* __restrict__ bfc, float* __restrict__ out) {
  const int n = blockIdx.x, l = threadIdx.x;    // 64 threads
  const int e = gate_idx[n];
  const float g = gate_val[n];
  const size_t pstride = (size_t)N_TOK*H_DIM/4;
  const float4* p0 = (const float4*)planes + (size_t)n*(H_DIM/4);
  const float4* b24 = (const float4*)(b2 + (size_t)e*H_DIM);
  const float2* w2 = (const float2*)Wfc;
  float a0 = 0.f, a1 = 0.f;
  #pragma unroll
  for (int j = 0; j < H_DIM/256; ++j) {
    const int i4 = j*64 + l;
    const float4 q0 = p0[i4];
    const float4 q1 = p0[i4 + pstride];
    const float4 q2 = p0[i4 + 2*pstride];
    const float4 q3 = p0[i4 + 3*pstride];
    const float4 bb = b24[i4];
    const float vx = (q0.x+q1.x+q2.x+q3.x + bb.x)*g;
    const float vy = (q0.y+q1.y+q2.y+q3.y + bb.y)*g;
    const float vz = (q0.z+q1.z+q2.z+q3.z + bb.z)*g;
    const float vw = (q0.w+q1.w+q2.w+q3.w + bb.w)*g;
    const int hh = i4*4;
    const float2 r0 = w2[hh], r1 = w2[hh+1], r2 = w2[hh+2], r3 = w2[hh+3];
    a0 += vx*r0.x + vy*r1.x + vz*r2.x + vw*r3.x;
    a1 += vx*r0.y + vy*r1.y + vz*r2.y + vw*r3.y;
  }
  #pragma unroll
  for (int m = 32; m >= 1; m >>= 1) { a0 += __shfl_xor(a0, m); a1 += __shfl_xor(a1, m); }
  if (l == 0) {
    const float l0 = a0 + bfc[0], l1 = a1 + bfc[1];
    const float mx = fmaxf(l0, l1);
    const float lse = mx + logf(expf(l0 - mx) + expf(l1 - mx));
    out[(size_t)n*2 + 0] = l0 - lse;
    out[(size_t)n*2 + 1] = l1 - lse;
  }
}

extern "C" void kernel_launch(void* const* d_in, const int* in_sizes, int n_in,
                              void* d_out, int out_size, void* d_ws, size_t ws_size,
                              hipStream_t stream) {
  const int*   x   = (const int*)  d_in[0];
  const float* emb = (const float*)d_in[1];
  const float* Wg  = (const float*)d_in[2];
  const float* W1  = (const float*)d_in[3];
  const float* b1  = (const float*)d_in[4];
  const float* W2  = (const float*)d_in[5];
  const float* b2  = (const float*)d_in[6];
  const float* Wfc = (const float*)d_in[7];
  const float* bfc = (const float*)d_in[8];
  float* out = (float*)d_out;

  char* p = (char*)d_ws;
  size_t off = 0;
  auto alloc = [&](size_t bytes) {
    void* r = p + off;
    off = (off + bytes + 255) & ~(size_t)255;
    return r;
  };
  u16*   hB       = (u16*)  alloc((size_t)N_TOK*H_DIM*2);
  float* gate_val = (float*)alloc((size_t)N_TOK*4);
  int*   gate_idx = (int*)  alloc((size_t)N_TOK*4);
  int*   perm     = (int*)  alloc((size_t)NPAD*4);
  int*   meta     = (int*)  alloc(256);
  int* cnt = meta; int* cursor = meta + 8; int* pad_off = meta + 16;  // 9 used
  u16* Hg  = (u16*)alloc((size_t)NPAD*H_DIM*2);
  u16* H1  = (u16*)alloc((size_t)NPAD*F_DIM*2);
  // union region: embf8 (51.2MB) dead before ct; W1T (67.1MB) dead after gemm1,
  // then reused as the SK2 f32 partial planes (4 x 16.8MB = 67.1MB). W2T live to gemm2.
  char* uni = (char*)alloc((size_t)E_NUM*F_DIM*H_DIM*2*2);
  u8*  embf8  = (u8*)uni;
  u16* W1T    = (u16*)uni;
  u16* W2T    = W1T + (size_t)E_NUM*F_DIM*H_DIM;
  float* planes = (float*)uni;   // aliases W1T region, stream-ordered

  hipMemsetAsync(meta, 0, 256, stream);
  embconv_kernel<<<4096, 256, 0, stream>>>(emb, embf8);
  poolgate_kernel<<<N_TOK, 256, 0, stream>>>(x, embf8, Wg, hB, gate_val, gate_idx, cnt);
  offsets_kernel<<<1, 1, 0, stream>>>(cnt, pad_off);
  scatterconv_kernel<<<N_TOK, 128, 0, stream>>>(hB, gate_idx, pad_off, cursor, perm, Hg);
  ct_kernel<F_DIM, H_DIM><<<dim3(F_DIM/64, E_NUM*H_DIM/64), 256, 0, stream>>>(W1, W1T);
  ct_kernel<H_DIM, F_DIM><<<dim3(H_DIM/64, E_NUM*F_DIM/64), 256, 0, stream>>>(W2, W2T);
  gemm_kernel<H_DIM, 1, 1><<<dim3(F_DIM/128, 32, E_NUM), 256, 0, stream>>>(
      W1T, Hg, b1, nullptr, pad_off, cnt, H1, nullptr);
  gemm_kernel<F_DIM, 2, SK2><<<dim3(H_DIM/128, 32, E_NUM*SK2), 256, 0, stream>>>(
      W2T, H1, nullptr, perm, pad_off, cnt, nullptr, planes);
  final_kernel<<<N_TOK, 64, 0, stream>>>(planes, b2, gate_idx, gate_val, Wfc, bfc, out);
}